// Round 4
// baseline (229.883 us; speedup 1.0000x reference)
//
#include <hip/hip_runtime.h>
#include <hip/hip_bf16.h>
#include <math.h>

#define B_   128
#define T_   256
#define C_   384
#define H_   6
#define HS_  64
#define NTOK (B_*T_)          // 32768
#define NQKV (3*C_)           // 1152

typedef unsigned short u16;
typedef __attribute__((ext_vector_type(8))) short bf16x8;   // 8 bf16 in 4 VGPRs
typedef __attribute__((ext_vector_type(4))) float f32x4;

__device__ __forceinline__ u16 f2b(float f) {
    unsigned int u = __builtin_bit_cast(unsigned int, f);
    unsigned int r = (u + 0x7FFFu + ((u >> 16) & 1u)) >> 16;   // RNE
    return (u16)r;
}

__device__ __forceinline__ float fexp2(float x) {
#if __has_builtin(__builtin_amdgcn_exp2f)
    return __builtin_amdgcn_exp2f(x);
#else
    return exp2f(x);
#endif
}

// async global->LDS, 16B per lane.  LDS dst = wave-uniform base + lane*16B.
__device__ __forceinline__ void gl2lds16(const u16* g, u16* l) {
    __builtin_amdgcn_global_load_lds(
        (const __attribute__((address_space(1))) unsigned int*)g,
        (__attribute__((address_space(3))) unsigned int*)l, 16, 0, 0);
}

// log2(e) * (1/sqrt(64)) folded into q at the qkv epilogue; attn uses exp2.
#define QSCALE 0.180336880f

// ---------------------------------------------------------------------------
// Fused prep: x->bf16 (8/thread), Wp->bf16 (8/thread), Wcat_t build (1/thread)
// ---------------------------------------------------------------------------
#define J0_ (NTOK*C_/8)     // 1,572,864
#define J2_ (C_*C_/8)       // 18,432
#define J1_ (NQKV*C_)       // 442,368

__global__ __launch_bounds__(256) void prep(
    const float* __restrict__ x,  const float* __restrict__ Wq,
    const float* __restrict__ Wk, const float* __restrict__ Wv,
    const float* __restrict__ Wp,
    u16* __restrict__ xb, u16* __restrict__ wct, u16* __restrict__ wpb)
{
    int i = blockIdx.x * 256 + threadIdx.x;
    if (i < J0_) {
        const float4* s = (const float4*)x + (size_t)i * 2;
        float4 a = s[0], b = s[1];
        ushort4 o1, o2;
        o1.x = f2b(a.x); o1.y = f2b(a.y); o1.z = f2b(a.z); o1.w = f2b(a.w);
        o2.x = f2b(b.x); o2.y = f2b(b.y); o2.z = f2b(b.z); o2.w = f2b(b.w);
        ((ushort4*)xb)[(size_t)i * 2]     = o1;
        ((ushort4*)xb)[(size_t)i * 2 + 1] = o2;
    } else if (i < J0_ + J2_) {
        int j = i - J0_;
        const float4* s = (const float4*)Wp + (size_t)j * 2;
        float4 a = s[0], b = s[1];
        ushort4 o1, o2;
        o1.x = f2b(a.x); o1.y = f2b(a.y); o1.z = f2b(a.z); o1.w = f2b(a.w);
        o2.x = f2b(b.x); o2.y = f2b(b.y); o2.z = f2b(b.z); o2.w = f2b(b.w);
        ((ushort4*)wpb)[(size_t)j * 2]     = o1;
        ((ushort4*)wpb)[(size_t)j * 2 + 1] = o2;
    } else {
        int j = i - J0_ - J2_;
        if (j < J1_) {
            int n = j / C_, c = j % C_;
            int p = n / C_, rem = n % C_;
            int h = rem >> 6, d = rem & 63;
            const float* W = (p == 0 ? Wq : (p == 1 ? Wk : Wv));
            wct[j] = f2b(W[(h * C_ + c) * HS_ + d]);
        }
    }
}

// ---------------------------------------------------------------------------
// Kernel 1: QKV GEMM.  xb[32768x384] @ wct^T.  q scaled by QSCALE.
// Grid 2304 linear, col-fastest (gid%9) for A-row L2/L3 reuse.
// q,k -> [b,h,t,d] via LDS-transpose epilogue (16B stores);
// v -> [b,h,d,t] packed 8B stores.
// ---------------------------------------------------------------------------
__global__ __launch_bounds__(256) void gemm_qkv(
    const u16* __restrict__ xb, const u16* __restrict__ wct,
    u16* __restrict__ qo, u16* __restrict__ ko, u16* __restrict__ vt)
{
    __shared__ __align__(16) u16 As[128 * 64];
    __shared__ __align__(16) u16 Bs[128 * 64];

    const int gid  = blockIdx.x;
    const int colb = gid % 9;
    const int rowb = gid / 9;
    const int m0g  = rowb * 128;
    const int n0g  = colb * 128;

    const int tid = threadIdx.x;
    const int w = tid >> 6, lane = tid & 63;
    const int lm = lane & 15, qd = lane >> 4;
    const int wm = (w & 1) * 64, wn = (w >> 1) * 64;

    // staging: wave w covers rows w*32..w*32+31 (4 insts x 8 rows)
    const int srow   = w * 32 + (lane >> 3);
    const int schunk = (lane & 7) ^ ((lane >> 3) & 7);   // XOR swizzle
    const u16* gA = xb  + (size_t)(m0g + srow) * C_ + schunk * 8;
    const u16* gB = wct + (size_t)(n0g + srow) * C_ + schunk * 8;
    u16* lA = &As[(w * 32) * 64];
    u16* lB = &Bs[(w * 32) * 64];

    f32x4 acc[4][4];
    #pragma unroll
    for (int mi = 0; mi < 4; ++mi)
        #pragma unroll
        for (int ni = 0; ni < 4; ++ni)
            acc[mi][ni] = (f32x4){0.f, 0.f, 0.f, 0.f};

    for (int k0 = 0; k0 < C_; k0 += 64) {
        __syncthreads();
        #pragma unroll
        for (int j = 0; j < 4; ++j) {
            gl2lds16(gA + j * 8 * C_, lA + j * 8 * 64);
            gl2lds16(gB + j * 8 * C_, lB + j * 8 * 64);
        }
        gA += 64; gB += 64;
        __syncthreads();

        #pragma unroll
        for (int ks = 0; ks < 2; ++ks) {
            bf16x8 af[4], bfr[4];
            #pragma unroll
            for (int mi = 0; mi < 4; ++mi) {
                const int row = wm + mi * 16 + lm;
                const int sl = (ks * 4 + qd) ^ (lm & 7);
                af[mi] = *(const bf16x8*)&As[row * 64 + sl * 8];
            }
            #pragma unroll
            for (int ni = 0; ni < 4; ++ni) {
                const int row = wn + ni * 16 + lm;
                const int sl = (ks * 4 + qd) ^ (lm & 7);
                bfr[ni] = *(const bf16x8*)&Bs[row * 64 + sl * 8];
            }
            #pragma unroll
            for (int mi = 0; mi < 4; ++mi)
                #pragma unroll
                for (int ni = 0; ni < 4; ++ni)
                    acc[mi][ni] = __builtin_amdgcn_mfma_f32_16x16x32_bf16(
                        af[mi], bfr[ni], acc[mi][ni], 0, 0, 0);
        }
    }

    const int bI = m0g >> 8;
    const int tBase = m0g & 255;

    if (colb < 6) {                      // q or k: LDS-transpose epilogue
        u16* dst = (colb < 3) ? qo : ko;
        const float scl = (colb < 3) ? QSCALE : 1.0f;
        const int hBase = (colb % 3) * 2;          // 2 heads per 128-col block
        u16 (*tb)[140] = (u16(*)[140])As;          // reuse As; pad 140 -> qd banks distinct
        const int rloc = tid >> 3;
        const int mg   = rloc >> 4;
        #pragma unroll
        for (int mi = 0; mi < 4; ++mi) {
            __syncthreads();
            #pragma unroll
            for (int ni = 0; ni < 4; ++ni)
                #pragma unroll
                for (int r = 0; r < 4; ++r)
                    tb[(w & 1) * 16 + qd * 4 + r][wn + ni * 16 + lm]
                        = f2b(acc[mi][ni][r] * scl);
            __syncthreads();
            const int t = tBase + mg * 64 + mi * 16 + (rloc & 15);
            #pragma unroll
            for (int j = 0; j < 2; ++j) {
                const int col = (tid & 7) * 8 + j * 64;
                const int h = hBase + (col >> 6);
                bf16x8 vv = *(const bf16x8*)&tb[rloc][col];
                *(bf16x8*)(dst + ((size_t)(bI * H_ + h) * T_ + t) * HS_ + (col & 63)) = vv;
            }
        }
    } else {                             // v: [b,h,d,t], 4 t's packed per store
        #pragma unroll
        for (int mi = 0; mi < 4; ++mi) {
            #pragma unroll
            for (int ni = 0; ni < 4; ++ni) {
                const int nn = (colb - 6) * 128 + wn + ni * 16 + lm;
                const int h = nn >> 6, d = nn & 63;
                const int t0 = tBase + wm + mi * 16 + qd * 4;
                ushort4 sv;
                sv.x = f2b(acc[mi][ni][0]); sv.y = f2b(acc[mi][ni][1]);
                sv.z = f2b(acc[mi][ni][2]); sv.w = f2b(acc[mi][ni][3]);
                *(ushort4*)(vt + ((size_t)(bI * H_ + h) * HS_ + d) * T_ + t0) = sv;
            }
        }
    }
}

// ---------------------------------------------------------------------------
// Kernel 2: flash attention, barrier-free main loop.
// Grid (B*H, 2), block 256.  Full K[256x64] + V^T[64x256] staged in LDS once.
// Each wave: 2 row-groups of 16 q-rows.  q pre-scaled by QSCALE (log2 domain).
// ---------------------------------------------------------------------------
__global__ __launch_bounds__(256) void attn_mfma(
    const u16* __restrict__ q, const u16* __restrict__ k,
    const u16* __restrict__ vt, u16* __restrict__ yb)
{
    __shared__ __align__(16) u16 Ks[256 * 64];    // [t][d], chunk-swizzled
    __shared__ __align__(16) u16 Vs[64 * 256];    // [d][t], chunk-swizzled
    __shared__ __align__(16) u16 Ps[4][16 * 72];  // per-wave P tile

    const int bh = blockIdx.x;
    const int qt = blockIdx.y;
    const int b = bh / H_, h = bh % H_;
    const int tid = threadIdx.x, w = tid >> 6, lane = tid & 63;
    const int lm = lane & 15, qd = lane >> 4;

    const u16* qb = q  + (size_t)bh * T_ * HS_;
    const u16* kb = k  + (size_t)bh * T_ * HS_;
    const u16* vb = vt + (size_t)bh * HS_ * T_;

    const int t0 = qt * 128 + w * 16;

    // Q fragments (direct global; overlaps staging)
    bf16x8 aq[2][2];
    #pragma unroll
    for (int rg = 0; rg < 2; ++rg) {
        const u16* qrow = qb + (size_t)(t0 + rg * 64 + lm) * HS_;
        aq[rg][0] = *(const bf16x8*)(qrow + qd * 8);
        aq[rg][1] = *(const bf16x8*)(qrow + 32 + qd * 8);
    }

    // Stage ALL of K and V^T (one barrier total).
    #pragma unroll
    for (int j = 0; j < 8; ++j) {
        {   // K: chunk L = (j*4+w)*64 + lane; row = L>>3, c = (L&7)^(row&7)
            const int L = (j * 4 + w) * 64 + lane;
            const int row = L >> 3;
            const int c = (L & 7) ^ (row & 7);
            gl2lds16(kb + (size_t)row * HS_ + c * 8, &Ks[(size_t)(j * 4 + w) * 512]);
        }
        {   // V: chunk L = (j*4+w)*64 + lane; d = L>>5, c = (L&31)^(d&15)
            const int L = (j * 4 + w) * 64 + lane;
            const int d = L >> 5;
            const int c = (L & 31) ^ (d & 15);
            gl2lds16(vb + (size_t)d * T_ + c * 8, &Vs[(size_t)(j * 4 + w) * 512]);
        }
    }

    f32x4 acc[2][4];
    float ms[2][4], ls[2][4];
    #pragma unroll
    for (int rg = 0; rg < 2; ++rg) {
        #pragma unroll
        for (int ni = 0; ni < 4; ++ni) acc[rg][ni] = (f32x4){0.f, 0.f, 0.f, 0.f};
        #pragma unroll
        for (int r = 0; r < 4; ++r) { ms[rg][r] = -INFINITY; ls[rg][r] = 0.f; }
    }

    __syncthreads();   // the only barrier before the epilogue

    u16* Pw = &Ps[w][0];
    const int nkt = (qt + 1) * 2;
    for (int kt = 0; kt < nkt; ++kt) {
        const int j0 = kt * 64;
        #pragma unroll
        for (int rg = 0; rg < 2; ++rg) {
            const int trg = t0 + rg * 64;
            if (j0 > trg + 15) continue;             // fully masked (wave-uniform)
            const bool needmask = (j0 + 63 > trg);

            // S = Q K^T  (16 x 64), log2-domain scores (q pre-scaled)
            f32x4 st[4];
            #pragma unroll
            for (int ni = 0; ni < 4; ++ni) st[ni] = (f32x4){0.f, 0.f, 0.f, 0.f};
            #pragma unroll
            for (int ks = 0; ks < 2; ++ks) {
                #pragma unroll
                for (int ni = 0; ni < 4; ++ni) {
                    const int row = j0 + ni * 16 + lm;
                    const int sl = (ks * 4 + qd) ^ (lm & 7);
                    bf16x8 bk = *(const bf16x8*)&Ks[row * 64 + sl * 8];
                    st[ni] = __builtin_amdgcn_mfma_f32_16x16x32_bf16(
                        aq[rg][ks], bk, st[ni], 0, 0, 0);
                }
            }

            // online softmax (base-2)
            float vals[4][4], rowmax[4];
            #pragma unroll
            for (int r = 0; r < 4; ++r) rowmax[r] = -INFINITY;
            #pragma unroll
            for (int ni = 0; ni < 4; ++ni) {
                const int s_g = j0 + ni * 16 + lm;
                #pragma unroll
                for (int r = 0; r < 4; ++r) {
                    float sc = st[ni][r];
                    if (needmask) {
                        const int t_g = trg + qd * 4 + r;
                        sc = (s_g > t_g) ? -1e30f : sc;
                    }
                    vals[ni][r] = sc;
                    rowmax[r] = fmaxf(rowmax[r], sc);
                }
            }
            #pragma unroll
            for (int msk = 1; msk <= 8; msk <<= 1)
                #pragma unroll
                for (int r = 0; r < 4; ++r)
                    rowmax[r] = fmaxf(rowmax[r], __shfl_xor(rowmax[r], msk, 64));

            float corr[4], rowsum[4];
            #pragma unroll
            for (int r = 0; r < 4; ++r) {
                const float mn = fmaxf(ms[rg][r], rowmax[r]);
                corr[r] = fexp2(ms[rg][r] - mn);
                ms[rg][r] = mn;
                rowsum[r] = 0.f;
            }
            #pragma unroll
            for (int ni = 0; ni < 4; ++ni) {
                #pragma unroll
                for (int r = 0; r < 4; ++r) {
                    const float p = fexp2(vals[ni][r] - ms[rg][r]);
                    rowsum[r] += p;
                    Pw[(qd * 4 + r) * 72 + ni * 16 + lm] = f2b(p);
                }
            }
            #pragma unroll
            for (int msk = 1; msk <= 8; msk <<= 1)
                #pragma unroll
                for (int r = 0; r < 4; ++r)
                    rowsum[r] += __shfl_xor(rowsum[r], msk, 64);
            #pragma unroll
            for (int r = 0; r < 4; ++r) ls[rg][r] = ls[rg][r] * corr[r] + rowsum[r];
            #pragma unroll
            for (int ni = 0; ni < 4; ++ni)
                #pragma unroll
                for (int r = 0; r < 4; ++r)
                    acc[rg][ni][r] *= corr[r];

            // PV: P via per-wave LDS (in-order DS pipe, no barrier)
            #pragma unroll
            for (int ks = 0; ks < 2; ++ks) {
                bf16x8 pa = *(const bf16x8*)&Pw[lm * 72 + ks * 32 + qd * 8];
                #pragma unroll
                for (int ni = 0; ni < 4; ++ni) {
                    const int d = ni * 16 + lm;
                    const int c = ((j0 >> 3) + ks * 4 + qd) ^ lm;   // ^ (d&15)
                    bf16x8 bv = *(const bf16x8*)&Vs[d * 256 + c * 8];
                    acc[rg][ni] = __builtin_amdgcn_mfma_f32_16x16x32_bf16(
                        pa, bv, acc[rg][ni], 0, 0, 0);
                }
            }
        }
    }

    // Epilogue: transpose via LDS (reuse Ks), 16B coalesced stores.
    __syncthreads();
    u16 (*yt)[72] = (u16(*)[72])Ks;
    #pragma unroll
    for (int rg = 0; rg < 2; ++rg)
        #pragma unroll
        for (int r = 0; r < 4; ++r) {
            const float inv = 1.f / ls[rg][r];
            #pragma unroll
            for (int ni = 0; ni < 4; ++ni)
                yt[w * 16 + rg * 64 + qd * 4 + r][ni * 16 + lm]
                    = f2b(acc[rg][ni][r] * inv);
        }
    __syncthreads();
    #pragma unroll
    for (int rr = 0; rr < 4; ++rr) {
        const int row = rr * 32 + (tid >> 3);
        const int col = (tid & 7) * 8;
        bf16x8 vv = *(const bf16x8*)&yt[row][col];
        const int t_g = qt * 128 + row;
        *(bf16x8*)(yb + ((size_t)(b * T_ + t_g)) * C_ + h * 64 + col) = vv;
    }
}

// ---------------------------------------------------------------------------
// Kernel 3: output projection.  yb[32768x384] @ wpb^T + bp -> fp32 out.
// Grid 768 linear, col-fastest (gid%3).  LDS-transpose fp32 epilogue.
// ---------------------------------------------------------------------------
__global__ __launch_bounds__(256) void gemm_proj(
    const u16* __restrict__ yb, const u16* __restrict__ wpb,
    const float* __restrict__ bp, float* __restrict__ out)
{
    __shared__ __align__(16) u16 SMEM[128 * 64 * 2];
    u16* As = SMEM;
    u16* Bs = SMEM + 128 * 64;

    const int gid  = blockIdx.x;
    const int colb = gid % 3;
    const int rowb = gid / 3;
    const int m0g  = rowb * 128;
    const int n0g  = colb * 128;

    const int tid = threadIdx.x;
    const int w = tid >> 6, lane = tid & 63;
    const int lm = lane & 15, qd = lane >> 4;
    const int wm = (w & 1) * 64, wn = (w >> 1) * 64;

    const int srow   = w * 32 + (lane >> 3);
    const int schunk = (lane & 7) ^ ((lane >> 3) & 7);
    const u16* gA = yb  + (size_t)(m0g + srow) * C_ + schunk * 8;
    const u16* gB = wpb + (size_t)(n0g + srow) * C_ + schunk * 8;
    u16* lA = &As[(w * 32) * 64];
    u16* lB = &Bs[(w * 32) * 64];

    f32x4 acc[4][4];
    #pragma unroll
    for (int mi = 0; mi < 4; ++mi)
        #pragma unroll
        for (int ni = 0; ni < 4; ++ni)
            acc[mi][ni] = (f32x4){0.f, 0.f, 0.f, 0.f};

    for (int k0 = 0; k0 < C_; k0 += 64) {
        __syncthreads();
        #pragma unroll
        for (int j = 0; j < 4; ++j) {
            gl2lds16(gA + j * 8 * C_, lA + j * 8 * 64);
            gl2lds16(gB + j * 8 * C_, lB + j * 8 * 64);
        }
        gA += 64; gB += 64;
        __syncthreads();

        #pragma unroll
        for (int ks = 0; ks < 2; ++ks) {
            bf16x8 af[4], bfr[4];
            #pragma unroll
            for (int mi = 0; mi < 4; ++mi) {
                const int row = wm + mi * 16 + lm;
                const int sl = (ks * 4 + qd) ^ (lm & 7);
                af[mi] = *(const bf16x8*)&As[row * 64 + sl * 8];
            }
            #pragma unroll
            for (int ni = 0; ni < 4; ++ni) {
                const int row = wn + ni * 16 + lm;
                const int sl = (ks * 4 + qd) ^ (lm & 7);
                bfr[ni] = *(const bf16x8*)&Bs[row * 64 + sl * 8];
            }
            #pragma unroll
            for (int mi = 0; mi < 4; ++mi)
                #pragma unroll
                for (int ni = 0; ni < 4; ++ni)
                    acc[mi][ni] = __builtin_amdgcn_mfma_f32_16x16x32_bf16(
                        af[mi], bfr[ni], acc[mi][ni], 0, 0, 0);
        }
    }

    // fp32 LDS-transpose epilogue with fused bias
    float bpv[4];
    #pragma unroll
    for (int ni = 0; ni < 4; ++ni) bpv[ni] = bp[n0g + wn + ni * 16 + lm];

    float (*tb)[134] = (float(*)[134])SMEM;   // 32x134 f32 = 17.2KB <= 32KB
    const int rloc = tid >> 3;
    const int mg   = rloc >> 4;
    #pragma unroll
    for (int mi = 0; mi < 4; ++mi) {
        __syncthreads();
        #pragma unroll
        for (int ni = 0; ni < 4; ++ni)
            #pragma unroll
            for (int r = 0; r < 4; ++r)
                tb[(w & 1) * 16 + qd * 4 + r][wn + ni * 16 + lm]
                    = acc[mi][ni][r] + bpv[ni];
        __syncthreads();
        const int m = m0g + mg * 64 + mi * 16 + (rloc & 15);
        #pragma unroll
        for (int j = 0; j < 4; ++j) {
            const int col = (tid & 7) * 4 + j * 32;
            float4 vv = *(const float4*)&tb[rloc][col];
            *(float4*)(out + (size_t)m * C_ + n0g + col) = vv;
        }
    }
}

// ---------------------------------------------------------------------------
extern "C" void kernel_launch(void* const* d_in, const int* in_sizes, int n_in,
                              void* d_out, int out_size, void* d_ws, size_t ws_size,
                              hipStream_t stream)
{
    const float* x  = (const float*)d_in[0];
    const float* Wq = (const float*)d_in[1];
    const float* Wk = (const float*)d_in[2];
    const float* Wv = (const float*)d_in[3];
    const float* Wp = (const float*)d_in[4];
    const float* bp = (const float*)d_in[5];
    float* out = (float*)d_out;

    u16* xb  = (u16*)d_ws;                         // 32768*384
    u16* wct = xb  + (size_t)NTOK * C_;            // 1152*384
    u16* wpb = wct + (size_t)NQKV * C_;            // 384*384
    u16* qo  = wpb + (size_t)C_ * C_;
    u16* ko  = qo  + (size_t)B_ * H_ * T_ * HS_;
    u16* vt  = ko  + (size_t)B_ * H_ * T_ * HS_;
    u16* yb  = vt  + (size_t)B_ * H_ * T_ * HS_;

    const int prep_blocks = (J0_ + J2_ + J1_ + 255) / 256;
    hipLaunchKernelGGL(prep, dim3(prep_blocks), dim3(256), 0, stream,
                       x, Wq, Wk, Wv, Wp, xb, wct, wpb);

    hipLaunchKernelGGL(gemm_qkv, dim3(NTOK / 128 * (NQKV / 128)), dim3(256), 0, stream,
                       xb, wct, qo, ko, vt);

    hipLaunchKernelGGL(attn_mfma, dim3(B_ * H_, T_ / 128), dim3(256), 0, stream,
                       qo, ko, vt, yb);

    hipLaunchKernelGGL(gemm_proj, dim3(NTOK / 128 * (C_ / 128)), dim3(256), 0, stream,
                       yb, wpb, bp, out);
}

// Round 5
// 220.344 us; speedup vs baseline: 1.0433x; 1.0433x over previous
//
#include <hip/hip_runtime.h>
#include <hip/hip_bf16.h>
#include <math.h>

#define B_   128
#define T_   256
#define C_   384
#define H_   6
#define HS_  64
#define NTOK (B_*T_)          // 32768
#define NQKV (3*C_)           // 1152

typedef unsigned short u16;
typedef __attribute__((ext_vector_type(8))) short bf16x8;   // 8 bf16 in 4 VGPRs
typedef __attribute__((ext_vector_type(4))) float f32x4;

__device__ __forceinline__ u16 f2b(float f) {
    unsigned int u = __builtin_bit_cast(unsigned int, f);
    unsigned int r = (u + 0x7FFFu + ((u >> 16) & 1u)) >> 16;   // RNE
    return (u16)r;
}

__device__ __forceinline__ float fexp2(float x) {
#if __has_builtin(__builtin_amdgcn_exp2f)
    return __builtin_amdgcn_exp2f(x);
#else
    return exp2f(x);
#endif
}

// async global->LDS, 16B per lane.  LDS dst = wave-uniform base + lane*16B.
__device__ __forceinline__ void gl2lds16(const u16* g, u16* l) {
    __builtin_amdgcn_global_load_lds(
        (const __attribute__((address_space(1))) unsigned int*)g,
        (__attribute__((address_space(3))) unsigned int*)l, 16, 0, 0);
}

// log2(e) * (1/sqrt(64)) folded into q at the qkv epilogue; attn uses exp2.
#define QSCALE 0.180336880f

// ---------------------------------------------------------------------------
// Fused prep: x->bf16 (8/thread), Wp->bf16 (8/thread), Wcat_t build (1/thread)
// ---------------------------------------------------------------------------
#define J0_ (NTOK*C_/8)     // 1,572,864
#define J2_ (C_*C_/8)       // 18,432
#define J1_ (NQKV*C_)       // 442,368

__global__ __launch_bounds__(256) void prep(
    const float* __restrict__ x,  const float* __restrict__ Wq,
    const float* __restrict__ Wk, const float* __restrict__ Wv,
    const float* __restrict__ Wp,
    u16* __restrict__ xb, u16* __restrict__ wct, u16* __restrict__ wpb)
{
    int i = blockIdx.x * 256 + threadIdx.x;
    if (i < J0_) {
        const float4* s = (const float4*)x + (size_t)i * 2;
        float4 a = s[0], b = s[1];
        ushort4 o1, o2;
        o1.x = f2b(a.x); o1.y = f2b(a.y); o1.z = f2b(a.z); o1.w = f2b(a.w);
        o2.x = f2b(b.x); o2.y = f2b(b.y); o2.z = f2b(b.z); o2.w = f2b(b.w);
        ((ushort4*)xb)[(size_t)i * 2]     = o1;
        ((ushort4*)xb)[(size_t)i * 2 + 1] = o2;
    } else if (i < J0_ + J2_) {
        int j = i - J0_;
        const float4* s = (const float4*)Wp + (size_t)j * 2;
        float4 a = s[0], b = s[1];
        ushort4 o1, o2;
        o1.x = f2b(a.x); o1.y = f2b(a.y); o1.z = f2b(a.z); o1.w = f2b(a.w);
        o2.x = f2b(b.x); o2.y = f2b(b.y); o2.z = f2b(b.z); o2.w = f2b(b.w);
        ((ushort4*)wpb)[(size_t)j * 2]     = o1;
        ((ushort4*)wpb)[(size_t)j * 2 + 1] = o2;
    } else {
        int j = i - J0_ - J2_;
        if (j < J1_) {
            int n = j / C_, c = j % C_;
            int p = n / C_, rem = n % C_;
            int h = rem >> 6, d = rem & 63;
            const float* W = (p == 0 ? Wq : (p == 1 ? Wk : Wv));
            wct[j] = f2b(W[(h * C_ + c) * HS_ + d]);
        }
    }
}

// ---------------------------------------------------------------------------
// Kernel 1: QKV GEMM.  xb[32768x384] @ wct^T.  q scaled by QSCALE.
// Grid 2304 linear.  XCD-affine swizzle: xcd = gid&7 (round-robin dispatch),
// all 9 col-blocks of one A-row-tile run consecutively on the SAME XCD so
// the 98KB A-tile is fetched once into that L2.  (Round-4 col-fastest
// mapping spread them over all 8 L2s: FETCH 62->115MB regression.)
// q,k -> [b,h,t,d] via LDS-transpose epilogue (16B stores);
// v -> [b,h,d,t] packed 8B stores.
// ---------------------------------------------------------------------------
__global__ __launch_bounds__(256) void gemm_qkv(
    const u16* __restrict__ xb, const u16* __restrict__ wct,
    u16* __restrict__ qo, u16* __restrict__ ko, u16* __restrict__ vt)
{
    __shared__ __align__(16) u16 As[128 * 64];
    __shared__ __align__(16) u16 Bs[128 * 64];

    const int gid  = blockIdx.x;
    const int xcd  = gid & 7;
    const int j_   = gid >> 3;          // 0..287
    const int colb = j_ % 9;
    const int rowb = (j_ / 9) * 8 + xcd;  // 0..255, rows striped per XCD
    const int m0g  = rowb * 128;
    const int n0g  = colb * 128;

    const int tid = threadIdx.x;
    const int w = tid >> 6, lane = tid & 63;
    const int lm = lane & 15, qd = lane >> 4;
    const int wm = (w & 1) * 64, wn = (w >> 1) * 64;

    // staging: wave w covers rows w*32..w*32+31 (4 insts x 8 rows)
    const int srow   = w * 32 + (lane >> 3);
    const int schunk = (lane & 7) ^ ((lane >> 3) & 7);   // XOR swizzle
    const u16* gA = xb  + (size_t)(m0g + srow) * C_ + schunk * 8;
    const u16* gB = wct + (size_t)(n0g + srow) * C_ + schunk * 8;
    u16* lA = &As[(w * 32) * 64];
    u16* lB = &Bs[(w * 32) * 64];

    f32x4 acc[4][4];
    #pragma unroll
    for (int mi = 0; mi < 4; ++mi)
        #pragma unroll
        for (int ni = 0; ni < 4; ++ni)
            acc[mi][ni] = (f32x4){0.f, 0.f, 0.f, 0.f};

    for (int k0 = 0; k0 < C_; k0 += 64) {
        __syncthreads();
        #pragma unroll
        for (int j = 0; j < 4; ++j) {
            gl2lds16(gA + j * 8 * C_, lA + j * 8 * 64);
            gl2lds16(gB + j * 8 * C_, lB + j * 8 * 64);
        }
        gA += 64; gB += 64;
        __syncthreads();

        #pragma unroll
        for (int ks = 0; ks < 2; ++ks) {
            bf16x8 af[4], bfr[4];
            #pragma unroll
            for (int mi = 0; mi < 4; ++mi) {
                const int row = wm + mi * 16 + lm;
                const int sl = (ks * 4 + qd) ^ (lm & 7);
                af[mi] = *(const bf16x8*)&As[row * 64 + sl * 8];
            }
            #pragma unroll
            for (int ni = 0; ni < 4; ++ni) {
                const int row = wn + ni * 16 + lm;
                const int sl = (ks * 4 + qd) ^ (lm & 7);
                bfr[ni] = *(const bf16x8*)&Bs[row * 64 + sl * 8];
            }
            #pragma unroll
            for (int mi = 0; mi < 4; ++mi)
                #pragma unroll
                for (int ni = 0; ni < 4; ++ni)
                    acc[mi][ni] = __builtin_amdgcn_mfma_f32_16x16x32_bf16(
                        af[mi], bfr[ni], acc[mi][ni], 0, 0, 0);
        }
    }

    const int bI = m0g >> 8;
    const int tBase = m0g & 255;

    if (colb < 6) {                      // q or k: LDS-transpose epilogue
        u16* dst = (colb < 3) ? qo : ko;
        const float scl = (colb < 3) ? QSCALE : 1.0f;
        const int hBase = (colb % 3) * 2;          // 2 heads per 128-col block
        u16 (*tb)[140] = (u16(*)[140])As;          // reuse As
        const int rloc = tid >> 3;
        const int mg   = rloc >> 4;
        #pragma unroll
        for (int mi = 0; mi < 4; ++mi) {
            __syncthreads();
            #pragma unroll
            for (int ni = 0; ni < 4; ++ni)
                #pragma unroll
                for (int r = 0; r < 4; ++r)
                    tb[(w & 1) * 16 + qd * 4 + r][wn + ni * 16 + lm]
                        = f2b(acc[mi][ni][r] * scl);
            __syncthreads();
            const int t = tBase + mg * 64 + mi * 16 + (rloc & 15);
            #pragma unroll
            for (int j = 0; j < 2; ++j) {
                const int col = (tid & 7) * 8 + j * 64;
                const int h = hBase + (col >> 6);
                bf16x8 vv = *(const bf16x8*)&tb[rloc][col];
                *(bf16x8*)(dst + ((size_t)(bI * H_ + h) * T_ + t) * HS_ + (col & 63)) = vv;
            }
        }
    } else {                             // v: [b,h,d,t], 4 t's packed per store
        #pragma unroll
        for (int mi = 0; mi < 4; ++mi) {
            #pragma unroll
            for (int ni = 0; ni < 4; ++ni) {
                const int nn = (colb - 6) * 128 + wn + ni * 16 + lm;
                const int h = nn >> 6, d = nn & 63;
                const int t0 = tBase + wm + mi * 16 + qd * 4;
                ushort4 sv;
                sv.x = f2b(acc[mi][ni][0]); sv.y = f2b(acc[mi][ni][1]);
                sv.z = f2b(acc[mi][ni][2]); sv.w = f2b(acc[mi][ni][3]);
                *(ushort4*)(vt + ((size_t)(bI * H_ + h) * HS_ + d) * T_ + t0) = sv;
            }
        }
    }
}

// ---------------------------------------------------------------------------
// Kernel 2: flash attention, barrier-free main loop.
// Grid (B*H, 2), block 256.  Full K[256x64] + V^T[64x256] staged in LDS once.
// (qt=0 and qt=1 blocks of one (b,h) are 768 apart; 768%8==0 -> same XCD,
//  K/V fetched once per L2.)
// ---------------------------------------------------------------------------
__global__ __launch_bounds__(256) void attn_mfma(
    const u16* __restrict__ q, const u16* __restrict__ k,
    const u16* __restrict__ vt, u16* __restrict__ yb)
{
    __shared__ __align__(16) u16 Ks[256 * 64];    // [t][d], chunk-swizzled
    __shared__ __align__(16) u16 Vs[64 * 256];    // [d][t], chunk-swizzled
    __shared__ __align__(16) u16 Ps[4][16 * 72];  // per-wave P tile

    const int bh = blockIdx.x;
    const int qt = blockIdx.y;
    const int b = bh / H_, h = bh % H_;
    const int tid = threadIdx.x, w = tid >> 6, lane = tid & 63;
    const int lm = lane & 15, qd = lane >> 4;

    const u16* qb = q  + (size_t)bh * T_ * HS_;
    const u16* kb = k  + (size_t)bh * T_ * HS_;
    const u16* vb = vt + (size_t)bh * HS_ * T_;

    const int t0 = qt * 128 + w * 16;

    // Q fragments (direct global; overlaps staging)
    bf16x8 aq[2][2];
    #pragma unroll
    for (int rg = 0; rg < 2; ++rg) {
        const u16* qrow = qb + (size_t)(t0 + rg * 64 + lm) * HS_;
        aq[rg][0] = *(const bf16x8*)(qrow + qd * 8);
        aq[rg][1] = *(const bf16x8*)(qrow + 32 + qd * 8);
    }

    // Stage ALL of K and V^T (one barrier total).
    #pragma unroll
    for (int j = 0; j < 8; ++j) {
        {   // K: chunk L = (j*4+w)*64 + lane; row = L>>3, c = (L&7)^(row&7)
            const int L = (j * 4 + w) * 64 + lane;
            const int row = L >> 3;
            const int c = (L & 7) ^ (row & 7);
            gl2lds16(kb + (size_t)row * HS_ + c * 8, &Ks[(size_t)(j * 4 + w) * 512]);
        }
        {   // V: chunk L = (j*4+w)*64 + lane; d = L>>5, c = (L&31)^(d&15)
            const int L = (j * 4 + w) * 64 + lane;
            const int d = L >> 5;
            const int c = (L & 31) ^ (d & 15);
            gl2lds16(vb + (size_t)d * T_ + c * 8, &Vs[(size_t)(j * 4 + w) * 512]);
        }
    }

    f32x4 acc[2][4];
    float ms[2][4], ls[2][4];
    #pragma unroll
    for (int rg = 0; rg < 2; ++rg) {
        #pragma unroll
        for (int ni = 0; ni < 4; ++ni) acc[rg][ni] = (f32x4){0.f, 0.f, 0.f, 0.f};
        #pragma unroll
        for (int r = 0; r < 4; ++r) { ms[rg][r] = -INFINITY; ls[rg][r] = 0.f; }
    }

    __syncthreads();   // the only barrier before the epilogue

    u16* Pw = &Ps[w][0];
    const int nkt = (qt + 1) * 2;
    for (int kt = 0; kt < nkt; ++kt) {
        const int j0 = kt * 64;
        #pragma unroll
        for (int rg = 0; rg < 2; ++rg) {
            const int trg = t0 + rg * 64;
            if (j0 > trg + 15) continue;             // fully masked (wave-uniform)
            const bool needmask = (j0 + 63 > trg);

            // S = Q K^T  (16 x 64), log2-domain scores (q pre-scaled)
            f32x4 st[4];
            #pragma unroll
            for (int ni = 0; ni < 4; ++ni) st[ni] = (f32x4){0.f, 0.f, 0.f, 0.f};
            #pragma unroll
            for (int ks = 0; ks < 2; ++ks) {
                #pragma unroll
                for (int ni = 0; ni < 4; ++ni) {
                    const int row = j0 + ni * 16 + lm;
                    const int sl = (ks * 4 + qd) ^ (lm & 7);
                    bf16x8 bk = *(const bf16x8*)&Ks[row * 64 + sl * 8];
                    st[ni] = __builtin_amdgcn_mfma_f32_16x16x32_bf16(
                        aq[rg][ks], bk, st[ni], 0, 0, 0);
                }
            }

            // online softmax (base-2)
            float vals[4][4], rowmax[4];
            #pragma unroll
            for (int r = 0; r < 4; ++r) rowmax[r] = -INFINITY;
            #pragma unroll
            for (int ni = 0; ni < 4; ++ni) {
                const int s_g = j0 + ni * 16 + lm;
                #pragma unroll
                for (int r = 0; r < 4; ++r) {
                    float sc = st[ni][r];
                    if (needmask) {
                        const int t_g = trg + qd * 4 + r;
                        sc = (s_g > t_g) ? -1e30f : sc;
                    }
                    vals[ni][r] = sc;
                    rowmax[r] = fmaxf(rowmax[r], sc);
                }
            }
            #pragma unroll
            for (int msk = 1; msk <= 8; msk <<= 1)
                #pragma unroll
                for (int r = 0; r < 4; ++r)
                    rowmax[r] = fmaxf(rowmax[r], __shfl_xor(rowmax[r], msk, 64));

            float corr[4], rowsum[4];
            #pragma unroll
            for (int r = 0; r < 4; ++r) {
                const float mn = fmaxf(ms[rg][r], rowmax[r]);
                corr[r] = fexp2(ms[rg][r] - mn);
                ms[rg][r] = mn;
                rowsum[r] = 0.f;
            }
            #pragma unroll
            for (int ni = 0; ni < 4; ++ni) {
                #pragma unroll
                for (int r = 0; r < 4; ++r) {
                    const float p = fexp2(vals[ni][r] - ms[rg][r]);
                    rowsum[r] += p;
                    Pw[(qd * 4 + r) * 72 + ni * 16 + lm] = f2b(p);
                }
            }
            #pragma unroll
            for (int msk = 1; msk <= 8; msk <<= 1)
                #pragma unroll
                for (int r = 0; r < 4; ++r)
                    rowsum[r] += __shfl_xor(rowsum[r], msk, 64);
            #pragma unroll
            for (int r = 0; r < 4; ++r) ls[rg][r] = ls[rg][r] * corr[r] + rowsum[r];
            #pragma unroll
            for (int ni = 0; ni < 4; ++ni)
                #pragma unroll
                for (int r = 0; r < 4; ++r)
                    acc[rg][ni][r] *= corr[r];

            // PV: P via per-wave LDS (in-order DS pipe, no barrier)
            #pragma unroll
            for (int ks = 0; ks < 2; ++ks) {
                bf16x8 pa = *(const bf16x8*)&Pw[lm * 72 + ks * 32 + qd * 8];
                #pragma unroll
                for (int ni = 0; ni < 4; ++ni) {
                    const int d = ni * 16 + lm;
                    const int c = ((j0 >> 3) + ks * 4 + qd) ^ lm;   // ^ (d&15)
                    bf16x8 bv = *(const bf16x8*)&Vs[d * 256 + c * 8];
                    acc[rg][ni] = __builtin_amdgcn_mfma_f32_16x16x32_bf16(
                        pa, bv, acc[rg][ni], 0, 0, 0);
                }
            }
        }
    }

    // Epilogue: transpose via LDS (reuse Ks), 16B coalesced stores.
    __syncthreads();
    u16 (*yt)[72] = (u16(*)[72])Ks;
    #pragma unroll
    for (int rg = 0; rg < 2; ++rg)
        #pragma unroll
        for (int r = 0; r < 4; ++r) {
            const float inv = 1.f / ls[rg][r];
            #pragma unroll
            for (int ni = 0; ni < 4; ++ni)
                yt[w * 16 + rg * 64 + qd * 4 + r][ni * 16 + lm]
                    = f2b(acc[rg][ni][r] * inv);
        }
    __syncthreads();
    #pragma unroll
    for (int rr = 0; rr < 4; ++rr) {
        const int row = rr * 32 + (tid >> 3);
        const int col = (tid & 7) * 8;
        bf16x8 vv = *(const bf16x8*)&yt[row][col];
        const int t_g = qt * 128 + row;
        *(bf16x8*)(yb + ((size_t)(b * T_ + t_g)) * C_ + h * 64 + col) = vv;
    }
}

// ---------------------------------------------------------------------------
// Kernel 3: output projection.  yb[32768x384] @ wpb^T + bp -> fp32 out.
// Grid 768 linear, XCD-affine swizzle (3 col-blocks per row consecutive on
// one XCD).  LDS-transpose fp32 epilogue.
// ---------------------------------------------------------------------------
__global__ __launch_bounds__(256) void gemm_proj(
    const u16* __restrict__ yb, const u16* __restrict__ wpb,
    const float* __restrict__ bp, float* __restrict__ out)
{
    __shared__ __align__(16) u16 SMEM[128 * 64 * 2];
    u16* As = SMEM;
    u16* Bs = SMEM + 128 * 64;

    const int gid  = blockIdx.x;
    const int xcd  = gid & 7;
    const int j_   = gid >> 3;            // 0..95
    const int colb = j_ % 3;
    const int rowb = (j_ / 3) * 8 + xcd;  // 0..255
    const int m0g  = rowb * 128;
    const int n0g  = colb * 128;

    const int tid = threadIdx.x;
    const int w = tid >> 6, lane = tid & 63;
    const int lm = lane & 15, qd = lane >> 4;
    const int wm = (w & 1) * 64, wn = (w >> 1) * 64;

    const int srow   = w * 32 + (lane >> 3);
    const int schunk = (lane & 7) ^ ((lane >> 3) & 7);
    const u16* gA = yb  + (size_t)(m0g + srow) * C_ + schunk * 8;
    const u16* gB = wpb + (size_t)(n0g + srow) * C_ + schunk * 8;
    u16* lA = &As[(w * 32) * 64];
    u16* lB = &Bs[(w * 32) * 64];

    f32x4 acc[4][4];
    #pragma unroll
    for (int mi = 0; mi < 4; ++mi)
        #pragma unroll
        for (int ni = 0; ni < 4; ++ni)
            acc[mi][ni] = (f32x4){0.f, 0.f, 0.f, 0.f};

    for (int k0 = 0; k0 < C_; k0 += 64) {
        __syncthreads();
        #pragma unroll
        for (int j = 0; j < 4; ++j) {
            gl2lds16(gA + j * 8 * C_, lA + j * 8 * 64);
            gl2lds16(gB + j * 8 * C_, lB + j * 8 * 64);
        }
        gA += 64; gB += 64;
        __syncthreads();

        #pragma unroll
        for (int ks = 0; ks < 2; ++ks) {
            bf16x8 af[4], bfr[4];
            #pragma unroll
            for (int mi = 0; mi < 4; ++mi) {
                const int row = wm + mi * 16 + lm;
                const int sl = (ks * 4 + qd) ^ (lm & 7);
                af[mi] = *(const bf16x8*)&As[row * 64 + sl * 8];
            }
            #pragma unroll
            for (int ni = 0; ni < 4; ++ni) {
                const int row = wn + ni * 16 + lm;
                const int sl = (ks * 4 + qd) ^ (lm & 7);
                bfr[ni] = *(const bf16x8*)&Bs[row * 64 + sl * 8];
            }
            #pragma unroll
            for (int mi = 0; mi < 4; ++mi)
                #pragma unroll
                for (int ni = 0; ni < 4; ++ni)
                    acc[mi][ni] = __builtin_amdgcn_mfma_f32_16x16x32_bf16(
                        af[mi], bfr[ni], acc[mi][ni], 0, 0, 0);
        }
    }

    // fp32 LDS-transpose epilogue with fused bias
    float bpv[4];
    #pragma unroll
    for (int ni = 0; ni < 4; ++ni) bpv[ni] = bp[n0g + wn + ni * 16 + lm];

    float (*tb)[134] = (float(*)[134])SMEM;
    const int rloc = tid >> 3;
    const int mg   = rloc >> 4;
    #pragma unroll
    for (int mi = 0; mi < 4; ++mi) {
        __syncthreads();
        #pragma unroll
        for (int ni = 0; ni < 4; ++ni)
            #pragma unroll
            for (int r = 0; r < 4; ++r)
                tb[(w & 1) * 16 + qd * 4 + r][wn + ni * 16 + lm]
                    = acc[mi][ni][r] + bpv[ni];
        __syncthreads();
        const int m = m0g + mg * 64 + mi * 16 + (rloc & 15);
        #pragma unroll
        for (int j = 0; j < 4; ++j) {
            const int col = (tid & 7) * 4 + j * 32;
            float4 vv = *(const float4*)&tb[rloc][col];
            *(float4*)(out + (size_t)m * C_ + n0g + col) = vv;
        }
    }
}

// ---------------------------------------------------------------------------
extern "C" void kernel_launch(void* const* d_in, const int* in_sizes, int n_in,
                              void* d_out, int out_size, void* d_ws, size_t ws_size,
                              hipStream_t stream)
{
    const float* x  = (const float*)d_in[0];
    const float* Wq = (const float*)d_in[1];
    const float* Wk = (const float*)d_in[2];
    const float* Wv = (const float*)d_in[3];
    const float* Wp = (const float*)d_in[4];
    const float* bp = (const float*)d_in[5];
    float* out = (float*)d_out;

    u16* xb  = (u16*)d_ws;                         // 32768*384
    u16* wct = xb  + (size_t)NTOK * C_;            // 1152*384
    u16* wpb = wct + (size_t)NQKV * C_;            // 384*384
    u16* qo  = wpb + (size_t)C_ * C_;
    u16* ko  = qo  + (size_t)B_ * H_ * T_ * HS_;
    u16* vt  = ko  + (size_t)B_ * H_ * T_ * HS_;
    u16* yb  = vt  + (size_t)B_ * H_ * T_ * HS_;

    const int prep_blocks = (J0_ + J2_ + J1_ + 255) / 256;
    hipLaunchKernelGGL(prep, dim3(prep_blocks), dim3(256), 0, stream,
                       x, Wq, Wk, Wv, Wp, xb, wct, wpb);

    hipLaunchKernelGGL(gemm_qkv, dim3(NTOK / 128 * (NQKV / 128)), dim3(256), 0, stream,
                       xb, wct, qo, ko, vt);

    hipLaunchKernelGGL(attn_mfma, dim3(B_ * H_, T_ / 128), dim3(256), 0, stream,
                       qo, ko, vt, yb);

    hipLaunchKernelGGL(gemm_proj, dim3(NTOK / 128 * (C_ / 128)), dim3(256), 0, stream,
                       yb, wpb, bp, out);
}

// Round 6
// 196.359 us; speedup vs baseline: 1.1707x; 1.1221x over previous
//
#include <hip/hip_runtime.h>
#include <hip/hip_bf16.h>
#include <math.h>

#define B_   128
#define T_   256
#define C_   384
#define H_   6
#define HS_  64
#define NTOK (B_*T_)          // 32768
#define NQKV (3*C_)           // 1152

typedef unsigned short u16;
typedef __attribute__((ext_vector_type(8))) short bf16x8;   // 8 bf16 in 4 VGPRs
typedef __attribute__((ext_vector_type(4))) float f32x4;

__device__ __forceinline__ u16 f2b(float f) {
    unsigned int u = __builtin_bit_cast(unsigned int, f);
    unsigned int r = (u + 0x7FFFu + ((u >> 16) & 1u)) >> 16;   // RNE
    return (u16)r;
}

__device__ __forceinline__ float fexp2(float x) {
#if __has_builtin(__builtin_amdgcn_exp2f)
    return __builtin_amdgcn_exp2f(x);
#else
    return exp2f(x);
#endif
}

// async global->LDS, 16B per lane.  LDS dst = wave-uniform base + lane*16B.
__device__ __forceinline__ void gl2lds16(const u16* g, u16* l) {
    __builtin_amdgcn_global_load_lds(
        (const __attribute__((address_space(1))) unsigned int*)g,
        (__attribute__((address_space(3))) unsigned int*)l, 16, 0, 0);
}

// log2(e) * (1/sqrt(64)) folded into q at the qkv epilogue; attn uses exp2.
#define QSCALE 0.180336880f

// ---------------------------------------------------------------------------
// Fused prep: x->bf16 (8/thread), Wp->bf16 (8/thread), Wcat_t build (1/thread)
// ---------------------------------------------------------------------------
#define J0_ (NTOK*C_/8)     // 1,572,864
#define J2_ (C_*C_/8)       // 18,432
#define J1_ (NQKV*C_)       // 442,368

__global__ __launch_bounds__(256) void prep(
    const float* __restrict__ x,  const float* __restrict__ Wq,
    const float* __restrict__ Wk, const float* __restrict__ Wv,
    const float* __restrict__ Wp,
    u16* __restrict__ xb, u16* __restrict__ wct, u16* __restrict__ wpb)
{
    int i = blockIdx.x * 256 + threadIdx.x;
    if (i < J0_) {
        const float4* s = (const float4*)x + (size_t)i * 2;
        float4 a = s[0], b = s[1];
        ushort4 o1, o2;
        o1.x = f2b(a.x); o1.y = f2b(a.y); o1.z = f2b(a.z); o1.w = f2b(a.w);
        o2.x = f2b(b.x); o2.y = f2b(b.y); o2.z = f2b(b.z); o2.w = f2b(b.w);
        ((ushort4*)xb)[(size_t)i * 2]     = o1;
        ((ushort4*)xb)[(size_t)i * 2 + 1] = o2;
    } else if (i < J0_ + J2_) {
        int j = i - J0_;
        const float4* s = (const float4*)Wp + (size_t)j * 2;
        float4 a = s[0], b = s[1];
        ushort4 o1, o2;
        o1.x = f2b(a.x); o1.y = f2b(a.y); o1.z = f2b(a.z); o1.w = f2b(a.w);
        o2.x = f2b(b.x); o2.y = f2b(b.y); o2.z = f2b(b.z); o2.w = f2b(b.w);
        ((ushort4*)wpb)[(size_t)j * 2]     = o1;
        ((ushort4*)wpb)[(size_t)j * 2 + 1] = o2;
    } else {
        int j = i - J0_ - J2_;
        if (j < J1_) {
            int n = j / C_, c = j % C_;
            int p = n / C_, rem = n % C_;
            int h = rem >> 6, d = rem & 63;
            const float* W = (p == 0 ? Wq : (p == 1 ? Wk : Wv));
            wct[j] = f2b(W[(h * C_ + c) * HS_ + d]);
        }
    }
}

// ---------------------------------------------------------------------------
// Kernel 1: QKV GEMM.  xb[32768x384] @ wct^T.  512 threads, 256x128 tile,
// 8 waves as 4(M)x2(N) 64x64 sub-tiles -> 16 waves/CU (2 blocks).
// XCD-affine: 9 col-blocks of one A-row-tile consecutive on one XCD.
// q,k -> [b,h,t,d] LDS-transpose epilogue; v -> [b,h,d,t] packed 8B stores.
// ---------------------------------------------------------------------------
__global__ __launch_bounds__(512, 4) void gemm_qkv(
    const u16* __restrict__ xb, const u16* __restrict__ wct,
    u16* __restrict__ qo, u16* __restrict__ ko, u16* __restrict__ vt)
{
    __shared__ __align__(16) u16 As[256 * 64];   // 32 KB
    __shared__ __align__(16) u16 Bs[128 * 64];   // 16 KB

    const int gid  = blockIdx.x;
    const int xcd  = gid & 7;
    const int j_   = gid >> 3;            // 0..143
    const int colb = j_ % 9;
    const int rowb = (j_ / 9) * 8 + xcd;  // 0..127
    const int m0g  = rowb * 256;          // spans exactly one batch b
    const int n0g  = colb * 128;

    const int tid = threadIdx.x;
    const int w = tid >> 6, lane = tid & 63;
    const int lm = lane & 15, qd = lane >> 4;
    const int wm = (w >> 1) * 64, wn = (w & 1) * 64;

    // staging: wave w -> A rows w*32..+31 (4 insts), B rows w*16..+15 (2 insts)
    const int schunk = (lane & 7) ^ ((lane >> 3) & 7);   // XOR swizzle
    const u16* gA = xb  + (size_t)(m0g + w * 32 + (lane >> 3)) * C_ + schunk * 8;
    const u16* gB = wct + (size_t)(n0g + w * 16 + (lane >> 3)) * C_ + schunk * 8;
    u16* lA = &As[(w * 32) * 64];
    u16* lB = &Bs[(w * 16) * 64];

    f32x4 acc[4][4];
    #pragma unroll
    for (int mi = 0; mi < 4; ++mi)
        #pragma unroll
        for (int ni = 0; ni < 4; ++ni)
            acc[mi][ni] = (f32x4){0.f, 0.f, 0.f, 0.f};

    for (int k0 = 0; k0 < C_; k0 += 64) {
        __syncthreads();
        #pragma unroll
        for (int j = 0; j < 4; ++j)
            gl2lds16(gA + j * 8 * C_, lA + j * 8 * 64);
        #pragma unroll
        for (int j = 0; j < 2; ++j)
            gl2lds16(gB + j * 8 * C_, lB + j * 8 * 64);
        gA += 64; gB += 64;
        __syncthreads();

        #pragma unroll
        for (int ks = 0; ks < 2; ++ks) {
            bf16x8 af[4], bfr[4];
            #pragma unroll
            for (int mi = 0; mi < 4; ++mi) {
                const int row = wm + mi * 16 + lm;
                const int sl = (ks * 4 + qd) ^ (lm & 7);
                af[mi] = *(const bf16x8*)&As[row * 64 + sl * 8];
            }
            #pragma unroll
            for (int ni = 0; ni < 4; ++ni) {
                const int row = wn + ni * 16 + lm;
                const int sl = (ks * 4 + qd) ^ (lm & 7);
                bfr[ni] = *(const bf16x8*)&Bs[row * 64 + sl * 8];
            }
            #pragma unroll
            for (int mi = 0; mi < 4; ++mi)
                #pragma unroll
                for (int ni = 0; ni < 4; ++ni)
                    acc[mi][ni] = __builtin_amdgcn_mfma_f32_16x16x32_bf16(
                        af[mi], bfr[ni], acc[mi][ni], 0, 0, 0);
        }
    }

    const int bI = m0g >> 8;   // tile == one full batch row-block (t 0..255)

    if (colb < 6) {                      // q or k: LDS-transpose epilogue
        u16* dst = (colb < 3) ? qo : ko;
        const float scl = (colb < 3) ? QSCALE : 1.0f;
        const int hBase = (colb % 3) * 2;          // 2 heads per 128-col block
        u16 (*tb)[136] = (u16(*)[136])As;          // 64x136 u16 = 17.4 KB
        const int rloc = tid >> 3;                 // 0..63
        #pragma unroll
        for (int mi = 0; mi < 4; ++mi) {
            __syncthreads();
            #pragma unroll
            for (int ni = 0; ni < 4; ++ni)
                #pragma unroll
                for (int r = 0; r < 4; ++r)
                    tb[(w >> 1) * 16 + qd * 4 + r][wn + ni * 16 + lm]
                        = f2b(acc[mi][ni][r] * scl);
            __syncthreads();
            const int t = (rloc >> 4) * 64 + mi * 16 + (rloc & 15);
            #pragma unroll
            for (int jj = 0; jj < 2; ++jj) {
                const int cc = (tid & 7) * 8 + jj * 64;
                const int h = hBase + (cc >> 6);
                bf16x8 vv = *(const bf16x8*)&tb[rloc][cc];
                *(bf16x8*)(dst + ((size_t)(bI * H_ + h) * T_ + t) * HS_ + (cc & 63)) = vv;
            }
        }
    } else {                             // v: [b,h,d,t], 4 t's packed per store
        #pragma unroll
        for (int mi = 0; mi < 4; ++mi) {
            #pragma unroll
            for (int ni = 0; ni < 4; ++ni) {
                const int nn = (colb - 6) * 128 + wn + ni * 16 + lm;
                const int h = nn >> 6, d = nn & 63;
                const int t0 = wm + mi * 16 + qd * 4;
                ushort4 sv;
                sv.x = f2b(acc[mi][ni][0]); sv.y = f2b(acc[mi][ni][1]);
                sv.z = f2b(acc[mi][ni][2]); sv.w = f2b(acc[mi][ni][3]);
                *(ushort4*)(vt + ((size_t)(bI * H_ + h) * HS_ + d) * T_ + t0) = sv;
            }
        }
    }
}

// ---------------------------------------------------------------------------
// Kernel 2: flash attention, phase-split staging (41 KB LDS -> 3 blocks/CU).
// Grid (B*H, 2), block 256.  Phase p stages K rows / V^T cols [p*128, p*128+128).
// qt=0 blocks run 1 phase; qt=1 run 2.  No barriers inside a phase.
// ---------------------------------------------------------------------------
__global__ __launch_bounds__(256, 3) void attn_mfma(
    const u16* __restrict__ q, const u16* __restrict__ k,
    const u16* __restrict__ vt, u16* __restrict__ yb)
{
    __shared__ __align__(16) u16 SM[128 * 64 + 64 * 128 + 4 * 16 * 72];  // 41 KB
    u16* Ks = SM;            // [128][64]  row-swizzled
    u16* Vs = SM + 8192;     // [64][128]  col-swizzled
    u16* Ps = SM + 16384;    // 4 x [16][72]

    const int bh = blockIdx.x;
    const int qt = blockIdx.y;
    const int b = bh / H_, h = bh % H_;
    const int tid = threadIdx.x, w = tid >> 6, lane = tid & 63;
    const int lm = lane & 15, qd = lane >> 4;

    const u16* qb = q  + (size_t)bh * T_ * HS_;
    const u16* kb = k  + (size_t)bh * T_ * HS_;
    const u16* vb = vt + (size_t)bh * HS_ * T_;

    const int t0 = qt * 128 + w * 16;

    bf16x8 aq[2][2];
    #pragma unroll
    for (int rg = 0; rg < 2; ++rg) {
        const u16* qrow = qb + (size_t)(t0 + rg * 64 + lm) * HS_;
        aq[rg][0] = *(const bf16x8*)(qrow + qd * 8);
        aq[rg][1] = *(const bf16x8*)(qrow + 32 + qd * 8);
    }

    f32x4 acc[2][4];
    float ms[2][4], ls[2][4];
    #pragma unroll
    for (int rg = 0; rg < 2; ++rg) {
        #pragma unroll
        for (int ni = 0; ni < 4; ++ni) acc[rg][ni] = (f32x4){0.f, 0.f, 0.f, 0.f};
        #pragma unroll
        for (int r = 0; r < 4; ++r) { ms[rg][r] = -INFINITY; ls[rg][r] = 0.f; }
    }

    u16* Pw = &Ps[w * 16 * 72];
    const int nph = qt + 1;

    for (int p = 0; p < nph; ++p) {
        if (p) __syncthreads();          // drain previous phase's consumers
        // stage K half: wave w -> rows w*32..+31 (4 insts)
        #pragma unroll
        for (int j = 0; j < 4; ++j) {
            const int row = w * 32 + j * 8 + (lane >> 3);
            const int c = (lane & 7) ^ (row & 7);
            gl2lds16(kb + (size_t)(p * 128 + row) * HS_ + c * 8,
                     &Ks[(w * 32 + j * 8) * 64]);
        }
        // stage V^T half: wave w -> d rows w*16..+15 (4 insts x 4 rows)
        #pragma unroll
        for (int j = 0; j < 4; ++j) {
            const int d = w * 16 + j * 4 + (lane >> 4);
            const int c = (lane & 15) ^ (d & 15);
            gl2lds16(vb + (size_t)d * T_ + p * 128 + c * 8,
                     &Vs[(w * 16 + j * 4) * 128]);
        }
        __syncthreads();

        for (int kt2 = 0; kt2 < 2; ++kt2) {
            const int j0 = p * 128 + kt2 * 64;
            #pragma unroll
            for (int rg = 0; rg < 2; ++rg) {
                const int trg = t0 + rg * 64;
                if (j0 > trg + 15) continue;         // fully masked (wave-uniform)
                const bool needmask = (j0 + 63 > trg);

                // S = Q K^T  (16 x 64)
                f32x4 st[4];
                #pragma unroll
                for (int ni = 0; ni < 4; ++ni) st[ni] = (f32x4){0.f, 0.f, 0.f, 0.f};
                #pragma unroll
                for (int ks = 0; ks < 2; ++ks) {
                    #pragma unroll
                    for (int ni = 0; ni < 4; ++ni) {
                        const int lrow = kt2 * 64 + ni * 16 + lm;
                        const int sl = (ks * 4 + qd) ^ (lm & 7);
                        bf16x8 bk = *(const bf16x8*)&Ks[lrow * 64 + sl * 8];
                        st[ni] = __builtin_amdgcn_mfma_f32_16x16x32_bf16(
                            aq[rg][ks], bk, st[ni], 0, 0, 0);
                    }
                }

                // online softmax (base-2; q pre-scaled by log2e/8)
                float vals[4][4], rowmax[4];
                #pragma unroll
                for (int r = 0; r < 4; ++r) rowmax[r] = -INFINITY;
                #pragma unroll
                for (int ni = 0; ni < 4; ++ni) {
                    const int s_g = j0 + ni * 16 + lm;
                    #pragma unroll
                    for (int r = 0; r < 4; ++r) {
                        float sc = st[ni][r];
                        if (needmask) {
                            const int t_g = trg + qd * 4 + r;
                            sc = (s_g > t_g) ? -1e30f : sc;
                        }
                        vals[ni][r] = sc;
                        rowmax[r] = fmaxf(rowmax[r], sc);
                    }
                }
                #pragma unroll
                for (int msk = 1; msk <= 8; msk <<= 1)
                    #pragma unroll
                    for (int r = 0; r < 4; ++r)
                        rowmax[r] = fmaxf(rowmax[r], __shfl_xor(rowmax[r], msk, 64));

                float corr[4], rowsum[4];
                #pragma unroll
                for (int r = 0; r < 4; ++r) {
                    const float mn = fmaxf(ms[rg][r], rowmax[r]);
                    corr[r] = fexp2(ms[rg][r] - mn);
                    ms[rg][r] = mn;
                    rowsum[r] = 0.f;
                }
                #pragma unroll
                for (int ni = 0; ni < 4; ++ni) {
                    #pragma unroll
                    for (int r = 0; r < 4; ++r) {
                        const float pv = fexp2(vals[ni][r] - ms[rg][r]);
                        rowsum[r] += pv;
                        Pw[(qd * 4 + r) * 72 + ni * 16 + lm] = f2b(pv);
                    }
                }
                #pragma unroll
                for (int msk = 1; msk <= 8; msk <<= 1)
                    #pragma unroll
                    for (int r = 0; r < 4; ++r)
                        rowsum[r] += __shfl_xor(rowsum[r], msk, 64);
                #pragma unroll
                for (int r = 0; r < 4; ++r) ls[rg][r] = ls[rg][r] * corr[r] + rowsum[r];
                #pragma unroll
                for (int ni = 0; ni < 4; ++ni)
                    #pragma unroll
                    for (int r = 0; r < 4; ++r)
                        acc[rg][ni][r] *= corr[r];

                // PV: P via per-wave LDS (in-order DS pipe, no barrier)
                #pragma unroll
                for (int ks = 0; ks < 2; ++ks) {
                    bf16x8 pa = *(const bf16x8*)&Pw[lm * 72 + ks * 32 + qd * 8];
                    #pragma unroll
                    for (int ni = 0; ni < 4; ++ni) {
                        const int d = ni * 16 + lm;
                        const int c = (kt2 * 8 + ks * 4 + qd) ^ lm;
                        bf16x8 bv = *(const bf16x8*)&Vs[d * 128 + c * 8];
                        acc[rg][ni] = __builtin_amdgcn_mfma_f32_16x16x32_bf16(
                            pa, bv, acc[rg][ni], 0, 0, 0);
                    }
                }
            }
        }
    }

    // Epilogue: transpose via LDS (reuse Ks/Vs region), 16B coalesced stores.
    __syncthreads();
    u16 (*yt)[72] = (u16(*)[72])SM;     // 128x72 = 18 KB <= 32 KB region
    #pragma unroll
    for (int rg = 0; rg < 2; ++rg)
        #pragma unroll
        for (int r = 0; r < 4; ++r) {
            const float inv = 1.f / ls[rg][r];
            #pragma unroll
            for (int ni = 0; ni < 4; ++ni)
                yt[w * 16 + rg * 64 + qd * 4 + r][ni * 16 + lm]
                    = f2b(acc[rg][ni][r] * inv);
        }
    __syncthreads();
    #pragma unroll
    for (int rr = 0; rr < 4; ++rr) {
        const int row = rr * 32 + (tid >> 3);
        const int col = (tid & 7) * 8;
        bf16x8 vv = *(const bf16x8*)&yt[row][col];
        const int t_g = qt * 128 + row;
        *(bf16x8*)(yb + ((size_t)(b * T_ + t_g)) * C_ + h * 64 + col) = vv;
    }
}

// ---------------------------------------------------------------------------
// Kernel 3: output projection.  yb[32768x384] @ wpb^T + bp -> fp32 out.
// 512 threads, 256x128 tile, XCD-affine, fp32 LDS-transpose epilogue.
// ---------------------------------------------------------------------------
__global__ __launch_bounds__(512, 4) void gemm_proj(
    const u16* __restrict__ yb, const u16* __restrict__ wpb,
    const float* __restrict__ bp, float* __restrict__ out)
{
    __shared__ __align__(16) u16 SMEM[256 * 64 + 128 * 64];   // 48 KB
    u16* As = SMEM;
    u16* Bs = SMEM + 256 * 64;

    const int gid  = blockIdx.x;
    const int xcd  = gid & 7;
    const int j_   = gid >> 3;            // 0..47
    const int colb = j_ % 3;
    const int rowb = (j_ / 3) * 8 + xcd;  // 0..127
    const int m0g  = rowb * 256;
    const int n0g  = colb * 128;

    const int tid = threadIdx.x;
    const int w = tid >> 6, lane = tid & 63;
    const int lm = lane & 15, qd = lane >> 4;
    const int wm = (w >> 1) * 64, wn = (w & 1) * 64;

    const int schunk = (lane & 7) ^ ((lane >> 3) & 7);
    const u16* gA = yb  + (size_t)(m0g + w * 32 + (lane >> 3)) * C_ + schunk * 8;
    const u16* gB = wpb + (size_t)(n0g + w * 16 + (lane >> 3)) * C_ + schunk * 8;
    u16* lA = &As[(w * 32) * 64];
    u16* lB = &Bs[(w * 16) * 64];

    f32x4 acc[4][4];
    #pragma unroll
    for (int mi = 0; mi < 4; ++mi)
        #pragma unroll
        for (int ni = 0; ni < 4; ++ni)
            acc[mi][ni] = (f32x4){0.f, 0.f, 0.f, 0.f};

    for (int k0 = 0; k0 < C_; k0 += 64) {
        __syncthreads();
        #pragma unroll
        for (int j = 0; j < 4; ++j)
            gl2lds16(gA + j * 8 * C_, lA + j * 8 * 64);
        #pragma unroll
        for (int j = 0; j < 2; ++j)
            gl2lds16(gB + j * 8 * C_, lB + j * 8 * 64);
        gA += 64; gB += 64;
        __syncthreads();

        #pragma unroll
        for (int ks = 0; ks < 2; ++ks) {
            bf16x8 af[4], bfr[4];
            #pragma unroll
            for (int mi = 0; mi < 4; ++mi) {
                const int row = wm + mi * 16 + lm;
                const int sl = (ks * 4 + qd) ^ (lm & 7);
                af[mi] = *(const bf16x8*)&As[row * 64 + sl * 8];
            }
            #pragma unroll
            for (int ni = 0; ni < 4; ++ni) {
                const int row = wn + ni * 16 + lm;
                const int sl = (ks * 4 + qd) ^ (lm & 7);
                bfr[ni] = *(const bf16x8*)&Bs[row * 64 + sl * 8];
            }
            #pragma unroll
            for (int mi = 0; mi < 4; ++mi)
                #pragma unroll
                for (int ni = 0; ni < 4; ++ni)
                    acc[mi][ni] = __builtin_amdgcn_mfma_f32_16x16x32_bf16(
                        af[mi], bfr[ni], acc[mi][ni], 0, 0, 0);
        }
    }

    // fp32 LDS-transpose epilogue with fused bias
    float bpv[4];
    #pragma unroll
    for (int ni = 0; ni < 4; ++ni) bpv[ni] = bp[n0g + wn + ni * 16 + lm];

    float (*tb)[132] = (float(*)[132])SMEM;   // 64x132 f32 = 33.8 KB <= 48 KB
    const int rloc = tid >> 3;                // 0..63
    #pragma unroll
    for (int mi = 0; mi < 4; ++mi) {
        __syncthreads();
        #pragma unroll
        for (int ni = 0; ni < 4; ++ni)
            #pragma unroll
            for (int r = 0; r < 4; ++r)
                tb[(w >> 1) * 16 + qd * 4 + r][wn + ni * 16 + lm]
                    = acc[mi][ni][r] + bpv[ni];
        __syncthreads();
        const int m = m0g + (rloc >> 4) * 64 + mi * 16 + (rloc & 15);
        #pragma unroll
        for (int jj = 0; jj < 4; ++jj) {
            const int cc = (tid & 7) * 4 + jj * 32;
            float4 vv = *(const float4*)&tb[rloc][cc];
            *(float4*)(out + (size_t)m * C_ + n0g + cc) = vv;
        }
    }
}

// ---------------------------------------------------------------------------
extern "C" void kernel_launch(void* const* d_in, const int* in_sizes, int n_in,
                              void* d_out, int out_size, void* d_ws, size_t ws_size,
                              hipStream_t stream)
{
    const float* x  = (const float*)d_in[0];
    const float* Wq = (const float*)d_in[1];
    const float* Wk = (const float*)d_in[2];
    const float* Wv = (const float*)d_in[3];
    const float* Wp = (const float*)d_in[4];
    const float* bp = (const float*)d_in[5];
    float* out = (float*)d_out;

    u16* xb  = (u16*)d_ws;                         // 32768*384
    u16* wct = xb  + (size_t)NTOK * C_;            // 1152*384
    u16* wpb = wct + (size_t)NQKV * C_;            // 384*384
    u16* qo  = wpb + (size_t)C_ * C_;
    u16* ko  = qo  + (size_t)B_ * H_ * T_ * HS_;
    u16* vt  = ko  + (size_t)B_ * H_ * T_ * HS_;
    u16* yb  = vt  + (size_t)B_ * H_ * T_ * HS_;

    const int prep_blocks = (J0_ + J2_ + J1_ + 255) / 256;
    hipLaunchKernelGGL(prep, dim3(prep_blocks), dim3(256), 0, stream,
                       x, Wq, Wk, Wv, Wp, xb, wct, wpb);

    hipLaunchKernelGGL(gemm_qkv, dim3((NTOK / 256) * (NQKV / 128)), dim3(512), 0, stream,
                       xb, wct, qo, ko, vt);

    hipLaunchKernelGGL(attn_mfma, dim3(B_ * H_, T_ / 128), dim3(256), 0, stream,
                       qo, ko, vt, yb);

    hipLaunchKernelGGL(gemm_proj, dim3((NTOK / 256) * (C_ / 128)), dim3(512), 0, stream,
                       yb, wpb, bp, out);
}